// Round 1
// baseline (1406.526 us; speedup 1.0000x reference)
//
#include <hip/hip_runtime.h>
#include <math.h>

#define TPB 64
#define NPT 270000
#define SOFTB 20.0f
#define CVGT 1e-5f
#define DVGT 1.0f
#define EPSB 1e-6f

__device__ __forceinline__ float softplus_f(float x) {
    // jax.nn.softplus = logaddexp(x, 0) = max(x,0) + log1p(exp(-|x|))
    return fmaxf(x, 0.0f) + __logf(1.0f + __expf(-fabsf(x)));
}

// Affine 4x4 inverse of the 9 INIT_BONES transforms.
__global__ void tinv_kernel(const float* __restrict__ tfs, float* __restrict__ tinv) {
    int c = threadIdx.x;
    if (c >= 9) return;
    const int bones[9] = {0, 1, 2, 4, 5, 16, 17, 18, 19};
    const float* T = tfs + bones[c] * 16;
    float r00=T[0], r01=T[1], r02=T[2],  t0=T[3];
    float r10=T[4], r11=T[5], r12=T[6],  t1=T[7];
    float r20=T[8], r21=T[9], r22=T[10], t2=T[11];
    float c00 = r11*r22 - r12*r21;
    float c01 = r12*r20 - r10*r22;
    float c02 = r10*r21 - r11*r20;
    float det = r00*c00 + r01*c01 + r02*c02;
    float id  = 1.0f / det;
    float i00=c00*id, i01=(r02*r21-r01*r22)*id, i02=(r01*r12-r02*r11)*id;
    float i10=c01*id, i11=(r00*r22-r02*r20)*id, i12=(r02*r10-r00*r12)*id;
    float i20=c02*id, i21=(r01*r20-r00*r21)*id, i22=(r00*r11-r01*r10)*id;
    float* O = tinv + c * 16;
    O[0]=i00; O[1]=i01; O[2]=i02;  O[3]=-(i00*t0+i01*t1+i02*t2);
    O[4]=i10; O[5]=i11; O[6]=i12;  O[7]=-(i10*t0+i11*t1+i12*t2);
    O[8]=i20; O[9]=i21; O[10]=i22; O[11]=-(i20*t0+i21*t1+i22*t2);
    O[12]=0.f; O[13]=0.f; O[14]=0.f; O[15]=1.f;
}

__global__ __launch_bounds__(TPB) void deform_kernel(
    const float* __restrict__ xd,
    const float* __restrict__ tfs,
    const float* __restrict__ W0, const float* __restrict__ b0,
    const float* __restrict__ W1, const float* __restrict__ b1,
    const float* __restrict__ W2, const float* __restrict__ b2,
    const float* __restrict__ tinv,
    float* __restrict__ out)
{
    // Per-thread hidden-activation column. Lane t owns arr[j*TPB + t]:
    // lanes consecutive -> 2 lanes/bank (free). No cross-thread sharing, no barriers.
    __shared__ float arr[64 * TPB];
    const int tid = threadIdx.x;
    const int p   = blockIdx.x * TPB + tid;
    const bool live = (p < NPT);
    const int pc = live ? p : 0;
    const int n  = pc / 9;
    const int c  = pc - n * 9;

    const float tx0 = xd[n*3+0], tx1 = xd[n*3+1], tx2 = xd[n*3+2];

    // xc_init = (T_inv[c] @ [xd,1])[:3]
    const float* Ti = tinv + c * 16;
    float x0 = fmaf(Ti[0], tx0, fmaf(Ti[1], tx1, fmaf(Ti[2],  tx2, Ti[3])));
    float x1 = fmaf(Ti[4], tx0, fmaf(Ti[5], tx1, fmaf(Ti[6],  tx2, Ti[7])));
    float x2 = fmaf(Ti[8], tx0, fmaf(Ti[9], tx1, fmaf(Ti[10], tx2, Ti[11])));

    float w[24];

    // Full forward: MLP -> softmax(20*m) -> LBS blend. Leaves h1 (softplus) in arr.
    auto forward = [&](float a0, float a1, float a2, float& o0, float& o1, float& o2) {
        // layer 1 (3 -> 64)
        #pragma unroll
        for (int j = 0; j < 64; ++j) {
            float z = fmaf(a0, W0[j], fmaf(a1, W0[64+j], fmaf(a2, W0[128+j], b0[j])));
            arr[j*TPB + tid] = softplus_f(z);
        }
        // layer 2 (64 -> 64): accumulators in regs (compile-time index), h0 from LDS
        float z1[64];
        #pragma unroll
        for (int j = 0; j < 64; ++j) z1[j] = b1[j];
        #pragma unroll 2
        for (int k = 0; k < 64; ++k) {
            float hk = arr[k*TPB + tid];
            #pragma unroll
            for (int j = 0; j < 64; ++j) z1[j] = fmaf(hk, W1[k*64 + j], z1[j]);
        }
        #pragma unroll
        for (int j = 0; j < 64; ++j) arr[j*TPB + tid] = softplus_f(z1[j]);
        // layer 3 (64 -> 24)
        float mo[24];
        #pragma unroll
        for (int q = 0; q < 24; ++q) mo[q] = b2[q];
        #pragma unroll 2
        for (int k = 0; k < 64; ++k) {
            float hk = arr[k*TPB + tid];
            #pragma unroll
            for (int q = 0; q < 24; ++q) mo[q] = fmaf(hk, W2[k*24 + q], mo[q]);
        }
        // softmax(SOFTB * mo)
        float mx = mo[0];
        #pragma unroll
        for (int q = 1; q < 24; ++q) mx = fmaxf(mx, mo[q]);
        float ssum = 0.f;
        #pragma unroll
        for (int q = 0; q < 24; ++q) { float e = __expf(SOFTB*(mo[q]-mx)); w[q] = e; ssum += e; }
        float inv = 1.0f / ssum;
        o0 = 0.f; o1 = 0.f; o2 = 0.f;
        #pragma unroll
        for (int q = 0; q < 24; ++q) {
            float wq = w[q] * inv; w[q] = wq;
            const float* Tn = tfs + q*16;
            float y0 = fmaf(Tn[0], a0, fmaf(Tn[1], a1, fmaf(Tn[2],  a2, Tn[3])));
            float y1 = fmaf(Tn[4], a0, fmaf(Tn[5], a1, fmaf(Tn[6],  a2, Tn[7])));
            float y2 = fmaf(Tn[8], a0, fmaf(Tn[9], a1, fmaf(Tn[10], a2, Tn[11])));
            o0 = fmaf(wq, y0, o0); o1 = fmaf(wq, y1, o1); o2 = fmaf(wq, y2, o2);
        }
    };

    // ---- init: forward at xc_init (gives gx and activations for the Jacobian) ----
    float f0, f1, f2;
    forward(x0, x1, x2, f0, f1, f2);

    // arr holds h1 = softplus(z1); convert in place to sigmoid(z1) = 1 - exp(-h1)
    #pragma unroll
    for (int j = 0; j < 64; ++j) {
        float h = arr[j*TPB + tid];
        arr[j*TPB + tid] = 1.0f - __expf(-h);
    }

    // Abar = sum_q w_q * A_q  (LBS linear part)
    float Ab[9] = {0.f,0.f,0.f,0.f,0.f,0.f,0.f,0.f,0.f};
    #pragma unroll
    for (int q = 0; q < 24; ++q) {
        const float* Tn = tfs + q*16;
        float wq = w[q];
        Ab[0]=fmaf(wq,Tn[0],Ab[0]); Ab[1]=fmaf(wq,Tn[1],Ab[1]); Ab[2]=fmaf(wq,Tn[2], Ab[2]);
        Ab[3]=fmaf(wq,Tn[4],Ab[3]); Ab[4]=fmaf(wq,Tn[5],Ab[4]); Ab[5]=fmaf(wq,Tn[6], Ab[5]);
        Ab[6]=fmaf(wq,Tn[8],Ab[6]); Ab[7]=fmaf(wq,Tn[9],Ab[7]); Ab[8]=fmaf(wq,Tn[10],Ab[8]);
    }

    // J via 3 forward-mode JVPs (tangent e_k). sigma(z0) recomputed on the fly.
    float J[9];
    #pragma unroll
    for (int kk = 0; kk < 3; ++kk) {
        float d1[64];
        #pragma unroll
        for (int j = 0; j < 64; ++j) d1[j] = 0.f;
        #pragma unroll 2
        for (int j = 0; j < 64; ++j) {
            float z  = fmaf(x0, W0[j], fmaf(x1, W0[64+j], fmaf(x2, W0[128+j], b0[j])));
            float s0 = 1.0f / (1.0f + __expf(-z));
            float dh0 = s0 * W0[kk*64 + j];
            #pragma unroll
            for (int j2 = 0; j2 < 64; ++j2) d1[j2] = fmaf(dh0, W1[j*64 + j2], d1[j2]);
        }
        float dm[24];
        #pragma unroll
        for (int q = 0; q < 24; ++q) dm[q] = 0.f;
        #pragma unroll
        for (int j2 = 0; j2 < 64; ++j2) {
            float dh1 = d1[j2] * arr[j2*TPB + tid];  // * sigma(z1)
            #pragma unroll
            for (int q = 0; q < 24; ++q) dm[q] = fmaf(dh1, W2[j2*24 + q], dm[q]);
        }
        // dw = S*(diag(w) - w w^T) dm ;  J[:,k] = Abar[:,k] + sum dw_n y_n
        float dot = 0.f, sA = 0.f, sB = 0.f, sC = 0.f;
        #pragma unroll
        for (int q = 0; q < 24; ++q) {
            float wd = w[q] * dm[q];
            dot += wd;
            const float* Tn = tfs + q*16;
            float y0 = fmaf(Tn[0], x0, fmaf(Tn[1], x1, fmaf(Tn[2],  x2, Tn[3])));
            float y1 = fmaf(Tn[4], x0, fmaf(Tn[5], x1, fmaf(Tn[6],  x2, Tn[7])));
            float y2 = fmaf(Tn[8], x0, fmaf(Tn[9], x1, fmaf(Tn[10], x2, Tn[11])));
            sA = fmaf(wd, y0, sA); sB = fmaf(wd, y1, sB); sC = fmaf(wd, y2, sC);
        }
        J[0+kk] = Ab[0+kk] + SOFTB*(sA - dot*f0);
        J[3+kk] = Ab[3+kk] + SOFTB*(sB - dot*f1);
        J[6+kk] = Ab[6+kk] + SOFTB*(sC - dot*f2);
    }

    // J_inv_init = inv(J) (adjugate)
    float m00=J[0],m01=J[1],m02=J[2],m10=J[3],m11=J[4],m12=J[5],m20=J[6],m21=J[7],m22=J[8];
    float c00=m11*m22-m12*m21, c01=m12*m20-m10*m22, c02=m10*m21-m11*m20;
    float det = m00*c00 + m01*c01 + m02*c02;
    float idet = 1.0f / det;
    float Ji0=c00*idet, Ji1=(m02*m21-m01*m22)*idet, Ji2=(m01*m12-m02*m11)*idet;
    float Ji3=c01*idet, Ji4=(m00*m22-m02*m20)*idet, Ji5=(m02*m10-m00*m12)*idet;
    float Ji6=c02*idet, Ji7=(m01*m20-m00*m21)*idet, Ji8=(m00*m11-m01*m10)*idet;

    // ---- Broyden ----
    float g0 = f0 - tx0, g1 = f1 - tx1, g2 = f2 - tx2;
    float gno = sqrtf(g0*g0 + g1*g1 + g2*g2);
    float u0 = -(Ji0*g0 + Ji1*g1 + Ji2*g2);
    float u1 = -(Ji3*g0 + Ji4*g1 + Ji5*g2);
    float u2 = -(Ji6*g0 + Ji7*g1 + Ji8*g2);
    bool valid = true;   // reference starts with ids_val = ones

    for (int it = 0; it < 20; ++it) {
        if (!__any((int)valid)) break;   // frozen lanes never unfreeze (mask logic)
        if (valid) {
            float dx0 = u0, dx1 = u1, dx2 = u2;
            x0 += dx0; x1 += dx1; x2 += dx2;
            float fn0, fn1, fn2;
            forward(x0, x1, x2, fn0, fn1, fn2);
            float ng0 = fn0 - tx0, ng1 = fn1 - tx1, ng2 = fn2 - tx2;
            float dg0 = ng0 - g0, dg1 = ng1 - g1, dg2 = ng2 - g2;
            g0 = ng0; g1 = ng1; g2 = ng2;
            float gn = sqrtf(g0*g0 + g1*g1 + g2*g2);
            gno = fminf(gn, gno);                  // NaN -> keeps old (matches where)
            valid = (gno > CVGT) && (gn < DVGT);   // NaN -> false (matches)
            if (valid) {
                // vT = dx^T J_inv ; a = dx - J_inv dg ; b = vT dg (+/- eps)
                float v0 = dx0*Ji0 + dx1*Ji3 + dx2*Ji6;
                float v1 = dx0*Ji1 + dx1*Ji4 + dx2*Ji7;
                float v2 = dx0*Ji2 + dx1*Ji5 + dx2*Ji8;
                float a0 = dx0 - (Ji0*dg0 + Ji1*dg1 + Ji2*dg2);
                float a1 = dx1 - (Ji3*dg0 + Ji4*dg1 + Ji5*dg2);
                float a2 = dx2 - (Ji6*dg0 + Ji7*dg1 + Ji8*dg2);
                float b = v0*dg0 + v1*dg1 + v2*dg2;
                b += (b >= 0.f) ? EPSB : -EPSB;
                float ib = 1.0f / b;
                a0 *= ib; a1 *= ib; a2 *= ib;
                Ji0 = fmaf(a0, v0, Ji0); Ji1 = fmaf(a0, v1, Ji1); Ji2 = fmaf(a0, v2, Ji2);
                Ji3 = fmaf(a1, v0, Ji3); Ji4 = fmaf(a1, v1, Ji4); Ji5 = fmaf(a1, v2, Ji5);
                Ji6 = fmaf(a2, v0, Ji6); Ji7 = fmaf(a2, v1, Ji7); Ji8 = fmaf(a2, v2, Ji8);
                u0 = -(Ji0*g0 + Ji1*g1 + Ji2*g2);
                u1 = -(Ji3*g0 + Ji4*g1 + Ji5*g2);
                u2 = -(Ji6*g0 + Ji7*g1 + Ji8*g2);
            }
        }
    }

    // correction is exactly zero in the forward pass -> output is xc_opt
    if (live) {
        out[p*3+0] = x0;
        out[p*3+1] = x1;
        out[p*3+2] = x2;
    }
}

extern "C" void kernel_launch(void* const* d_in, const int* in_sizes, int n_in,
                              void* d_out, int out_size, void* d_ws, size_t ws_size,
                              hipStream_t stream) {
    const float* xd  = (const float*)d_in[0];
    const float* tfs = (const float*)d_in[1];
    const float* W0  = (const float*)d_in[2];
    const float* b0  = (const float*)d_in[3];
    const float* W1  = (const float*)d_in[4];
    const float* b1  = (const float*)d_in[5];
    const float* W2  = (const float*)d_in[6];
    const float* b2  = (const float*)d_in[7];
    float* out  = (float*)d_out;
    float* tinv = (float*)d_ws;   // 9 * 16 floats

    tinv_kernel<<<1, 16, 0, stream>>>(tfs, tinv);
    int nblk = (NPT + TPB - 1) / TPB;
    deform_kernel<<<nblk, TPB, 0, stream>>>(xd, tfs, W0, b0, W1, b1, W2, b2, tinv, out);
}

// Round 2
// 1128.831 us; speedup vs baseline: 1.2460x; 1.2460x over previous
//
#include <hip/hip_runtime.h>
#include <math.h>

#define TPB 64
#define NPT 270000
#define SOFTB 20.0f
#define CVGT 1e-5f
#define DVGT 1.0f
#define EPSB 1e-6f

// ws float offsets
#define WS_TINV 0      // 9*16 = 144 floats
#define WS_W0T  256    // 64*4 floats: cols 0..2 = W0 row k, col 3 = b0[k]
#define WS_W2T  512    // 24*64 floats: W2T[q][j] = W2[j][q]

__global__ void prep_kernel(const float* __restrict__ tfs,
                            const float* __restrict__ W0, const float* __restrict__ b0,
                            const float* __restrict__ W2,
                            float* __restrict__ ws) {
    int t = threadIdx.x;   // 256 threads, 1 block
    if (t < 9) {
        const int bones[9] = {0, 1, 2, 4, 5, 16, 17, 18, 19};
        const float* T = tfs + bones[t] * 16;
        float r00=T[0], r01=T[1], r02=T[2],  t0=T[3];
        float r10=T[4], r11=T[5], r12=T[6],  t1=T[7];
        float r20=T[8], r21=T[9], r22=T[10], t2=T[11];
        float c00 = r11*r22 - r12*r21;
        float c01 = r12*r20 - r10*r22;
        float c02 = r10*r21 - r11*r20;
        float det = r00*c00 + r01*c01 + r02*c02;
        float id  = 1.0f / det;
        float i00=c00*id, i01=(r02*r21-r01*r22)*id, i02=(r01*r12-r02*r11)*id;
        float i10=c01*id, i11=(r00*r22-r02*r20)*id, i12=(r02*r10-r00*r12)*id;
        float i20=c02*id, i21=(r01*r20-r00*r21)*id, i22=(r00*r11-r01*r10)*id;
        float* O = ws + WS_TINV + t * 16;
        O[0]=i00; O[1]=i01; O[2]=i02;  O[3]=-(i00*t0+i01*t1+i02*t2);
        O[4]=i10; O[5]=i11; O[6]=i12;  O[7]=-(i10*t0+i11*t1+i12*t2);
        O[8]=i20; O[9]=i21; O[10]=i22; O[11]=-(i20*t0+i21*t1+i22*t2);
        O[12]=0.f; O[13]=0.f; O[14]=0.f; O[15]=1.f;
    }
    for (int i = t; i < 64*4; i += 256) {
        int k = i >> 2, cidx = i & 3;
        ws[WS_W0T + i] = (cidx < 3) ? W0[cidx*64 + k] : b0[k];
    }
    for (int i = t; i < 24*64; i += 256) {
        int q = i >> 6, j = i & 63;
        ws[WS_W2T + i] = W2[j*24 + q];
    }
}

__global__ __launch_bounds__(TPB, 4) void deform_kernel(
    const float* __restrict__ xd,
    const float* __restrict__ tfs,
    const float* __restrict__ W1, const float* __restrict__ b1,
    const float* __restrict__ W2, const float* __restrict__ b2,
    const float* __restrict__ ws,
    float* __restrict__ out)
{
    // per-thread LDS column: slots [0..23] = mo / softmax w, [24..32] = J (row-major)
    __shared__ float lds[33 * TPB];
    const int tid = threadIdx.x;
    const int p   = blockIdx.x * TPB + tid;
    const bool live = (p < NPT);
    const int pc = live ? p : 0;
    const int n  = pc / 9;
    const int c  = pc - n * 9;

    const float tx0 = xd[n*3+0], tx1 = xd[n*3+1], tx2 = xd[n*3+2];

    const float* Ti  = ws + WS_TINV + c * 16;
    const float* W0T = ws + WS_W0T;
    const float* W2T = ws + WS_W2T;

    float x0 = fmaf(Ti[0], tx0, fmaf(Ti[1], tx1, fmaf(Ti[2],  tx2, Ti[3])));
    float x1 = fmaf(Ti[4], tx0, fmaf(Ti[5], tx1, fmaf(Ti[6],  tx2, Ti[7])));
    float x2 = fmaf(Ti[8], tx0, fmaf(Ti[9], tx1, fmaf(Ti[10], tx2, Ti[11])));

    float h1[64];   // layer-2 accumulators / activations (always static-indexed)

    // forward: MLP -> softmax(20*m) -> LBS blend; leaves h1=softplus(z1) in regs,
    // softmax weights w in lds[0..23].
    auto forward = [&](float a0, float a1, float a2, float& o0, float& o1, float& o2) {
        #pragma unroll
        for (int j = 0; j < 64; ++j) h1[j] = b1[j];
        // fused layer1+layer2: recompute z0_k, softplus, rank-1 update of z1
        #pragma unroll 2
        for (int k = 0; k < 64; ++k) {
            float w0a = W0T[k*4+0], w0b = W0T[k*4+1], w0c = W0T[k*4+2], w0d = W0T[k*4+3];
            float z  = fmaf(a0, w0a, fmaf(a1, w0b, fmaf(a2, w0c, w0d)));
            float hk = fmaxf(z, 0.f) + __logf(1.f + __expf(-fabsf(z)));
            const float* Wr = W1 + k*64;
            #pragma unroll
            for (int j = 0; j < 64; ++j) h1[j] = fmaf(hk, Wr[j], h1[j]);
        }
        #pragma unroll
        for (int j = 0; j < 64; ++j) {
            float z = h1[j];
            h1[j] = fmaxf(z, 0.f) + __logf(1.f + __expf(-fabsf(z)));
        }
        // layer 3 (rolled over q; W2T rows contiguous) -> mo into LDS
        for (int q = 0; q < 24; ++q) {
            float acc = b2[q];
            const float* Wq = W2T + q*64;
            #pragma unroll
            for (int j = 0; j < 64; ++j) acc = fmaf(h1[j], Wq[j], acc);
            lds[q*TPB + tid] = acc;
        }
        // softmax(SOFTB * mo) in LDS
        float mx = lds[tid];
        for (int q = 1; q < 24; ++q) mx = fmaxf(mx, lds[q*TPB + tid]);
        float ssum = 0.f;
        for (int q = 0; q < 24; ++q) {
            float e = __expf(SOFTB * (lds[q*TPB + tid] - mx));
            lds[q*TPB + tid] = e; ssum += e;
        }
        float inv = 1.0f / ssum;
        o0 = 0.f; o1 = 0.f; o2 = 0.f;
        for (int q = 0; q < 24; ++q) {
            float wq = lds[q*TPB + tid] * inv;
            lds[q*TPB + tid] = wq;
            const float* Tn = tfs + q*16;
            float y0 = fmaf(Tn[0], a0, fmaf(Tn[1], a1, fmaf(Tn[2],  a2, Tn[3])));
            float y1 = fmaf(Tn[4], a0, fmaf(Tn[5], a1, fmaf(Tn[6],  a2, Tn[7])));
            float y2 = fmaf(Tn[8], a0, fmaf(Tn[9], a1, fmaf(Tn[10], a2, Tn[11])));
            o0 = fmaf(wq, y0, o0); o1 = fmaf(wq, y1, o1); o2 = fmaf(wq, y2, o2);
        }
    };

    // ---- init forward ----
    float f0, f1, f2;
    forward(x0, x1, x2, f0, f1, f2);

    // h1 -> sigma(z1) in place (exact: sigma(z) = 1 - exp(-softplus(z)))
    #pragma unroll
    for (int j = 0; j < 64; ++j) h1[j] = 1.0f - __expf(-h1[j]);

    // ---- analytic Jacobian via 3 JVPs (tangent t), chunked d1 ----
    for (int t = 0; t < 3; ++t) {
        float dm[24];
        #pragma unroll
        for (int q = 0; q < 24; ++q) dm[q] = 0.f;
        #pragma unroll
        for (int cc = 0; cc < 4; ++cc) {
            float d1c[16];
            #pragma unroll
            for (int j = 0; j < 16; ++j) d1c[j] = 0.f;
            #pragma unroll 2
            for (int k = 0; k < 64; ++k) {
                float w0a = W0T[k*4+0], w0b = W0T[k*4+1], w0c = W0T[k*4+2], w0d = W0T[k*4+3];
                float z  = fmaf(x0, w0a, fmaf(x1, w0b, fmaf(x2, w0c, w0d)));
                float sg = 1.0f / (1.0f + __expf(-z));     // sigma(z0_k)
                float dh0 = sg * W0T[k*4 + t];
                const float* Wr = W1 + k*64 + cc*16;
                #pragma unroll
                for (int j = 0; j < 16; ++j) d1c[j] = fmaf(dh0, Wr[j], d1c[j]);
            }
            #pragma unroll
            for (int j = 0; j < 16; ++j) {
                float dh1 = d1c[j] * h1[cc*16 + j];        // * sigma(z1)
                const float* Wr = W2 + (cc*16 + j)*24;
                #pragma unroll
                for (int q = 0; q < 24; ++q) dm[q] = fmaf(dh1, Wr[q], dm[q]);
            }
        }
        // reduce to J column t: J[:,t] = Ab[:,t] + S*(sum w dm y - (sum w dm) f)
        float dot=0.f, sA=0.f, sB=0.f, sC=0.f, ab0=0.f, ab1=0.f, ab2=0.f;
        #pragma unroll
        for (int q = 0; q < 24; ++q) {
            float wq = lds[q*TPB + tid];
            float wd = wq * dm[q];
            dot += wd;
            const float* Tn = tfs + q*16;
            float y0 = fmaf(Tn[0], x0, fmaf(Tn[1], x1, fmaf(Tn[2],  x2, Tn[3])));
            float y1 = fmaf(Tn[4], x0, fmaf(Tn[5], x1, fmaf(Tn[6],  x2, Tn[7])));
            float y2 = fmaf(Tn[8], x0, fmaf(Tn[9], x1, fmaf(Tn[10], x2, Tn[11])));
            sA = fmaf(wd, y0, sA); sB = fmaf(wd, y1, sB); sC = fmaf(wd, y2, sC);
            ab0 = fmaf(wq, Tn[0 + t], ab0);
            ab1 = fmaf(wq, Tn[4 + t], ab1);
            ab2 = fmaf(wq, Tn[8 + t], ab2);
        }
        lds[(24 + 0*3 + t)*TPB + tid] = ab0 + SOFTB*(sA - dot*f0);
        lds[(24 + 1*3 + t)*TPB + tid] = ab1 + SOFTB*(sB - dot*f1);
        lds[(24 + 2*3 + t)*TPB + tid] = ab2 + SOFTB*(sC - dot*f2);
    }

    // J_inv_init = inv(J) (adjugate)
    float m00 = lds[(24+0)*TPB+tid], m01 = lds[(24+1)*TPB+tid], m02 = lds[(24+2)*TPB+tid];
    float m10 = lds[(24+3)*TPB+tid], m11 = lds[(24+4)*TPB+tid], m12 = lds[(24+5)*TPB+tid];
    float m20 = lds[(24+6)*TPB+tid], m21 = lds[(24+7)*TPB+tid], m22 = lds[(24+8)*TPB+tid];
    float c00 = m11*m22 - m12*m21, c01 = m12*m20 - m10*m22, c02 = m10*m21 - m11*m20;
    float det = m00*c00 + m01*c01 + m02*c02;
    float idet = 1.0f / det;
    float Ji0=c00*idet, Ji1=(m02*m21-m01*m22)*idet, Ji2=(m01*m12-m02*m11)*idet;
    float Ji3=c01*idet, Ji4=(m00*m22-m02*m20)*idet, Ji5=(m02*m10-m00*m12)*idet;
    float Ji6=c02*idet, Ji7=(m01*m20-m00*m21)*idet, Ji8=(m00*m11-m01*m10)*idet;

    // ---- Broyden ----
    float g0 = f0 - tx0, g1 = f1 - tx1, g2 = f2 - tx2;
    float gno = sqrtf(g0*g0 + g1*g1 + g2*g2);
    float u0 = -(Ji0*g0 + Ji1*g1 + Ji2*g2);
    float u1 = -(Ji3*g0 + Ji4*g1 + Ji5*g2);
    float u2 = -(Ji6*g0 + Ji7*g1 + Ji8*g2);
    bool valid = true;

    for (int it = 0; it < 20; ++it) {
        if (!__any((int)valid)) break;
        if (valid) {
            float dx0 = u0, dx1 = u1, dx2 = u2;
            x0 += dx0; x1 += dx1; x2 += dx2;
            float fn0, fn1, fn2;
            forward(x0, x1, x2, fn0, fn1, fn2);
            float ng0 = fn0 - tx0, ng1 = fn1 - tx1, ng2 = fn2 - tx2;
            float dg0 = ng0 - g0, dg1 = ng1 - g1, dg2 = ng2 - g2;
            g0 = ng0; g1 = ng1; g2 = ng2;
            float gn = sqrtf(g0*g0 + g1*g1 + g2*g2);
            gno = fminf(gn, gno);                  // NaN keeps old (matches where)
            valid = (gno > CVGT) && (gn < DVGT);   // NaN -> false (matches)
            if (valid) {
                float v0 = dx0*Ji0 + dx1*Ji3 + dx2*Ji6;
                float v1 = dx0*Ji1 + dx1*Ji4 + dx2*Ji7;
                float v2 = dx0*Ji2 + dx1*Ji5 + dx2*Ji8;
                float a0 = dx0 - (Ji0*dg0 + Ji1*dg1 + Ji2*dg2);
                float a1 = dx1 - (Ji3*dg0 + Ji4*dg1 + Ji5*dg2);
                float a2 = dx2 - (Ji6*dg0 + Ji7*dg1 + Ji8*dg2);
                float b = v0*dg0 + v1*dg1 + v2*dg2;
                b += (b >= 0.f) ? EPSB : -EPSB;
                float ib = 1.0f / b;
                a0 *= ib; a1 *= ib; a2 *= ib;
                Ji0 = fmaf(a0, v0, Ji0); Ji1 = fmaf(a0, v1, Ji1); Ji2 = fmaf(a0, v2, Ji2);
                Ji3 = fmaf(a1, v0, Ji3); Ji4 = fmaf(a1, v1, Ji4); Ji5 = fmaf(a1, v2, Ji5);
                Ji6 = fmaf(a2, v0, Ji6); Ji7 = fmaf(a2, v1, Ji7); Ji8 = fmaf(a2, v2, Ji8);
                u0 = -(Ji0*g0 + Ji1*g1 + Ji2*g2);
                u1 = -(Ji3*g0 + Ji4*g1 + Ji5*g2);
                u2 = -(Ji6*g0 + Ji7*g1 + Ji8*g2);
            }
        }
    }

    if (live) {
        out[p*3+0] = x0;
        out[p*3+1] = x1;
        out[p*3+2] = x2;
    }
}

extern "C" void kernel_launch(void* const* d_in, const int* in_sizes, int n_in,
                              void* d_out, int out_size, void* d_ws, size_t ws_size,
                              hipStream_t stream) {
    const float* xd  = (const float*)d_in[0];
    const float* tfs = (const float*)d_in[1];
    const float* W0  = (const float*)d_in[2];
    const float* b0  = (const float*)d_in[3];
    const float* W1  = (const float*)d_in[4];
    const float* b1  = (const float*)d_in[5];
    const float* W2  = (const float*)d_in[6];
    const float* b2  = (const float*)d_in[7];
    float* out = (float*)d_out;
    float* ws  = (float*)d_ws;

    prep_kernel<<<1, 256, 0, stream>>>(tfs, W0, b0, W2, ws);
    int nblk = (NPT + TPB - 1) / TPB;
    deform_kernel<<<nblk, TPB, 0, stream>>>(xd, tfs, W1, b1, W2, b2, ws, out);
}

// Round 3
// 872.664 us; speedup vs baseline: 1.6118x; 1.2935x over previous
//
#include <hip/hip_runtime.h>
#include <math.h>

#define TPB 64
#define NPT 270000
#define SOFTB 20.0f
#define CVGT 1e-5f
#define DVGT 1.0f
#define EPSB 1e-6f

// ws float offsets
#define WS_TINV 0      // 9*16 = 144 floats
#define WS_W0T  256    // 64*4 floats: cols 0..2 = W0 row k, col 3 = b0[k]

__global__ void prep_kernel(const float* __restrict__ tfs,
                            const float* __restrict__ W0, const float* __restrict__ b0,
                            float* __restrict__ ws) {
    int t = threadIdx.x;   // 256 threads, 1 block
    if (t < 9) {
        const int bones[9] = {0, 1, 2, 4, 5, 16, 17, 18, 19};
        const float* T = tfs + bones[t] * 16;
        float r00=T[0], r01=T[1], r02=T[2],  t0=T[3];
        float r10=T[4], r11=T[5], r12=T[6],  t1=T[7];
        float r20=T[8], r21=T[9], r22=T[10], t2=T[11];
        float c00 = r11*r22 - r12*r21;
        float c01 = r12*r20 - r10*r22;
        float c02 = r10*r21 - r11*r20;
        float det = r00*c00 + r01*c01 + r02*c02;
        float id  = 1.0f / det;
        float i00=c00*id, i01=(r02*r21-r01*r22)*id, i02=(r01*r12-r02*r11)*id;
        float i10=c01*id, i11=(r00*r22-r02*r20)*id, i12=(r02*r10-r00*r12)*id;
        float i20=c02*id, i21=(r01*r20-r00*r21)*id, i22=(r00*r11-r01*r10)*id;
        float* O = ws + WS_TINV + t * 16;
        O[0]=i00; O[1]=i01; O[2]=i02;  O[3]=-(i00*t0+i01*t1+i02*t2);
        O[4]=i10; O[5]=i11; O[6]=i12;  O[7]=-(i10*t0+i11*t1+i12*t2);
        O[8]=i20; O[9]=i21; O[10]=i22; O[11]=-(i20*t0+i21*t1+i22*t2);
        O[12]=0.f; O[13]=0.f; O[14]=0.f; O[15]=1.f;
    }
    for (int i = t; i < 64*4; i += 256) {
        int k = i >> 2, cidx = i & 3;
        ws[WS_W0T + i] = (cidx < 3) ? W0[cidx*64 + k] : b0[k];
    }
}

__global__ __launch_bounds__(TPB)
__attribute__((amdgpu_waves_per_eu(4, 4)))
void deform_kernel(
    const float* __restrict__ xd,
    const float* __restrict__ tfs,
    const float* __restrict__ W1, const float* __restrict__ b1,
    const float* __restrict__ W2, const float* __restrict__ b2,
    const float* __restrict__ ws,
    float* __restrict__ out)
{
    // per-thread LDS column: slots [0..23] = softmax w, [24..32] = J (row-major)
    __shared__ float lds[33 * TPB];
    const int tid = threadIdx.x;
    const int p   = blockIdx.x * TPB + tid;
    const bool live = (p < NPT);
    const int pc = live ? p : 0;
    const int n  = pc / 9;
    const int c  = pc - n * 9;

    const float tx0 = xd[n*3+0], tx1 = xd[n*3+1], tx2 = xd[n*3+2];

    const float* Ti  = ws + WS_TINV + c * 16;
    const float* W0T = ws + WS_W0T;

    float x0 = fmaf(Ti[0], tx0, fmaf(Ti[1], tx1, fmaf(Ti[2],  tx2, Ti[3])));
    float x1 = fmaf(Ti[4], tx0, fmaf(Ti[5], tx1, fmaf(Ti[6],  tx2, Ti[7])));
    float x2 = fmaf(Ti[8], tx0, fmaf(Ti[9], tx1, fmaf(Ti[10], tx2, Ti[11])));

    float h1[64];   // layer-2 accumulators / activations (always static-indexed)

    // forward: MLP -> softmax(20*m) -> LBS blend.
    // Leaves h1 = softplus(z1) in regs and softmax weights w in lds[0..23].
    auto forward = [&](float a0, float a1, float a2, float& o0, float& o1, float& o2) {
        #pragma unroll
        for (int j = 0; j < 64; ++j) h1[j] = b1[j];
        // fused layer1+layer2: recompute z0_k, softplus, rank-1 update of z1
        #pragma unroll 2
        for (int k = 0; k < 64; ++k) {
            float w0a = W0T[k*4+0], w0b = W0T[k*4+1], w0c = W0T[k*4+2], w0d = W0T[k*4+3];
            float z  = fmaf(a0, w0a, fmaf(a1, w0b, fmaf(a2, w0c, w0d)));
            float hk = fmaxf(z, 0.f) + __logf(1.f + __expf(-fabsf(z)));
            const float* Wr = W1 + k*64;
            #pragma unroll
            for (int j = 0; j < 64; ++j) h1[j] = fmaf(hk, Wr[j], h1[j]);
        }
        #pragma unroll
        for (int j = 0; j < 64; ++j) {
            float z = h1[j];
            h1[j] = fmaxf(z, 0.f) + __logf(1.f + __expf(-fabsf(z)));
        }
        // layer 3 (64 -> 24), mo in registers, W2 row-major (uniform s_loads)
        float mo[24];
        #pragma unroll
        for (int q = 0; q < 24; ++q) mo[q] = b2[q];
        #pragma unroll 2
        for (int k = 0; k < 64; ++k) {
            float hk = h1[k];
            const float* Wr = W2 + k*24;
            #pragma unroll
            for (int q = 0; q < 24; ++q) mo[q] = fmaf(hk, Wr[q], mo[q]);
        }
        // softmax(SOFTB * mo), fully unrolled in regs
        float mx = mo[0];
        #pragma unroll
        for (int q = 1; q < 24; ++q) mx = fmaxf(mx, mo[q]);
        float ssum = 0.f;
        #pragma unroll
        for (int q = 0; q < 24; ++q) { float e = __expf(SOFTB*(mo[q]-mx)); mo[q] = e; ssum += e; }
        float inv = 1.0f / ssum;
        o0 = 0.f; o1 = 0.f; o2 = 0.f;
        #pragma unroll
        for (int q = 0; q < 24; ++q) {
            float wq = mo[q] * inv;
            lds[q*TPB + tid] = wq;          // persist for Jacobian
            const float* Tn = tfs + q*16;
            float y0 = fmaf(Tn[0], a0, fmaf(Tn[1], a1, fmaf(Tn[2],  a2, Tn[3])));
            float y1 = fmaf(Tn[4], a0, fmaf(Tn[5], a1, fmaf(Tn[6],  a2, Tn[7])));
            float y2 = fmaf(Tn[8], a0, fmaf(Tn[9], a1, fmaf(Tn[10], a2, Tn[11])));
            o0 = fmaf(wq, y0, o0); o1 = fmaf(wq, y1, o1); o2 = fmaf(wq, y2, o2);
        }
    };

    // ---- init forward ----
    float f0, f1, f2;
    forward(x0, x1, x2, f0, f1, f2);

    // h1 -> sigma(z1) in place (exact: sigma(z) = 1 - exp(-softplus(z)))
    #pragma unroll
    for (int j = 0; j < 64; ++j) h1[j] = 1.0f - __expf(-h1[j]);

    // ---- analytic Jacobian via 3 JVPs (tangent t), chunked d1 ----
    for (int t = 0; t < 3; ++t) {
        float dm[24];
        #pragma unroll
        for (int q = 0; q < 24; ++q) dm[q] = 0.f;
        #pragma unroll
        for (int cc = 0; cc < 4; ++cc) {
            float d1c[16];
            #pragma unroll
            for (int j = 0; j < 16; ++j) d1c[j] = 0.f;
            #pragma unroll 2
            for (int k = 0; k < 64; ++k) {
                float w0a = W0T[k*4+0], w0b = W0T[k*4+1], w0c = W0T[k*4+2], w0d = W0T[k*4+3];
                float z  = fmaf(x0, w0a, fmaf(x1, w0b, fmaf(x2, w0c, w0d)));
                float sg = 1.0f / (1.0f + __expf(-z));     // sigma(z0_k)
                float dh0 = sg * W0T[k*4 + t];
                const float* Wr = W1 + k*64 + cc*16;
                #pragma unroll
                for (int j = 0; j < 16; ++j) d1c[j] = fmaf(dh0, Wr[j], d1c[j]);
            }
            #pragma unroll
            for (int j = 0; j < 16; ++j) {
                float dh1 = d1c[j] * h1[cc*16 + j];        // * sigma(z1)
                const float* Wr = W2 + (cc*16 + j)*24;
                #pragma unroll
                for (int q = 0; q < 24; ++q) dm[q] = fmaf(dh1, Wr[q], dm[q]);
            }
        }
        // reduce to J column t: J[:,t] = Ab[:,t] + S*(sum w dm y - (sum w dm) f)
        float dot=0.f, sA=0.f, sB=0.f, sC=0.f, ab0=0.f, ab1=0.f, ab2=0.f;
        #pragma unroll
        for (int q = 0; q < 24; ++q) {
            float wq = lds[q*TPB + tid];
            float wd = wq * dm[q];
            dot += wd;
            const float* Tn = tfs + q*16;
            float y0 = fmaf(Tn[0], x0, fmaf(Tn[1], x1, fmaf(Tn[2],  x2, Tn[3])));
            float y1 = fmaf(Tn[4], x0, fmaf(Tn[5], x1, fmaf(Tn[6],  x2, Tn[7])));
            float y2 = fmaf(Tn[8], x0, fmaf(Tn[9], x1, fmaf(Tn[10], x2, Tn[11])));
            sA = fmaf(wd, y0, sA); sB = fmaf(wd, y1, sB); sC = fmaf(wd, y2, sC);
            ab0 = fmaf(wq, Tn[0 + t], ab0);
            ab1 = fmaf(wq, Tn[4 + t], ab1);
            ab2 = fmaf(wq, Tn[8 + t], ab2);
        }
        lds[(24 + 0*3 + t)*TPB + tid] = ab0 + SOFTB*(sA - dot*f0);
        lds[(24 + 1*3 + t)*TPB + tid] = ab1 + SOFTB*(sB - dot*f1);
        lds[(24 + 2*3 + t)*TPB + tid] = ab2 + SOFTB*(sC - dot*f2);
    }

    // J_inv_init = inv(J) (adjugate)
    float m00 = lds[(24+0)*TPB+tid], m01 = lds[(24+1)*TPB+tid], m02 = lds[(24+2)*TPB+tid];
    float m10 = lds[(24+3)*TPB+tid], m11 = lds[(24+4)*TPB+tid], m12 = lds[(24+5)*TPB+tid];
    float m20 = lds[(24+6)*TPB+tid], m21 = lds[(24+7)*TPB+tid], m22 = lds[(24+8)*TPB+tid];
    float c00 = m11*m22 - m12*m21, c01 = m12*m20 - m10*m22, c02 = m10*m21 - m11*m20;
    float det = m00*c00 + m01*c01 + m02*c02;
    float idet = 1.0f / det;
    float Ji0=c00*idet, Ji1=(m02*m21-m01*m22)*idet, Ji2=(m01*m12-m02*m11)*idet;
    float Ji3=c01*idet, Ji4=(m00*m22-m02*m20)*idet, Ji5=(m02*m10-m00*m12)*idet;
    float Ji6=c02*idet, Ji7=(m01*m20-m00*m21)*idet, Ji8=(m00*m11-m01*m10)*idet;

    // ---- Broyden ----
    float g0 = f0 - tx0, g1 = f1 - tx1, g2 = f2 - tx2;
    float gno = sqrtf(g0*g0 + g1*g1 + g2*g2);
    float u0 = -(Ji0*g0 + Ji1*g1 + Ji2*g2);
    float u1 = -(Ji3*g0 + Ji4*g1 + Ji5*g2);
    float u2 = -(Ji6*g0 + Ji7*g1 + Ji8*g2);
    bool valid = true;

    for (int it = 0; it < 20; ++it) {
        if (!__any((int)valid)) break;
        if (valid) {
            float dx0 = u0, dx1 = u1, dx2 = u2;
            x0 += dx0; x1 += dx1; x2 += dx2;
            float fn0, fn1, fn2;
            forward(x0, x1, x2, fn0, fn1, fn2);
            float ng0 = fn0 - tx0, ng1 = fn1 - tx1, ng2 = fn2 - tx2;
            float dg0 = ng0 - g0, dg1 = ng1 - g1, dg2 = ng2 - g2;
            g0 = ng0; g1 = ng1; g2 = ng2;
            float gn = sqrtf(g0*g0 + g1*g1 + g2*g2);
            gno = fminf(gn, gno);                  // NaN keeps old (matches where)
            valid = (gno > CVGT) && (gn < DVGT);   // NaN -> false (matches)
            if (valid) {
                float v0 = dx0*Ji0 + dx1*Ji3 + dx2*Ji6;
                float v1 = dx0*Ji1 + dx1*Ji4 + dx2*Ji7;
                float v2 = dx0*Ji2 + dx1*Ji5 + dx2*Ji8;
                float a0 = dx0 - (Ji0*dg0 + Ji1*dg1 + Ji2*dg2);
                float a1 = dx1 - (Ji3*dg0 + Ji4*dg1 + Ji5*dg2);
                float a2 = dx2 - (Ji6*dg0 + Ji7*dg1 + Ji8*dg2);
                float b = v0*dg0 + v1*dg1 + v2*dg2;
                b += (b >= 0.f) ? EPSB : -EPSB;
                float ib = 1.0f / b;
                a0 *= ib; a1 *= ib; a2 *= ib;
                Ji0 = fmaf(a0, v0, Ji0); Ji1 = fmaf(a0, v1, Ji1); Ji2 = fmaf(a0, v2, Ji2);
                Ji3 = fmaf(a1, v0, Ji3); Ji4 = fmaf(a1, v1, Ji4); Ji5 = fmaf(a1, v2, Ji5);
                Ji6 = fmaf(a2, v0, Ji6); Ji7 = fmaf(a2, v1, Ji7); Ji8 = fmaf(a2, v2, Ji8);
                u0 = -(Ji0*g0 + Ji1*g1 + Ji2*g2);
                u1 = -(Ji3*g0 + Ji4*g1 + Ji5*g2);
                u2 = -(Ji6*g0 + Ji7*g1 + Ji8*g2);
            }
        }
    }

    if (live) {
        out[p*3+0] = x0;
        out[p*3+1] = x1;
        out[p*3+2] = x2;
    }
}

extern "C" void kernel_launch(void* const* d_in, const int* in_sizes, int n_in,
                              void* d_out, int out_size, void* d_ws, size_t ws_size,
                              hipStream_t stream) {
    const float* xd  = (const float*)d_in[0];
    const float* tfs = (const float*)d_in[1];
    const float* W0  = (const float*)d_in[2];
    const float* b0  = (const float*)d_in[3];
    const float* W1  = (const float*)d_in[4];
    const float* b1  = (const float*)d_in[5];
    const float* W2  = (const float*)d_in[6];
    const float* b2  = (const float*)d_in[7];
    float* out = (float*)d_out;
    float* ws  = (float*)d_ws;

    prep_kernel<<<1, 256, 0, stream>>>(tfs, W0, b0, ws);
    int nblk = (NPT + TPB - 1) / TPB;
    deform_kernel<<<nblk, TPB, 0, stream>>>(xd, tfs, W1, b1, W2, b2, ws, out);
}